// Round 8
// baseline (15250.124 us; speedup 1.0000x reference)
//
#include <hip/hip_runtime.h>

#define NF 8
#define RD 256
#define RMASK 255

typedef float f2 __attribute__((ext_vector_type(2)));
typedef float f4 __attribute__((ext_vector_type(4)));

template <int CTRL>
__device__ __forceinline__ float qp(float x) {
  return __int_as_float(
      __builtin_amdgcn_update_dpp(0, __float_as_int(x), CTRL, 0xF, 0xF, true));
}

// Raw barrier: LDS-ordering only (global ops stay in flight across phases).
__device__ __forceinline__ void wg_barrier() {
  asm volatile("s_waitcnt lgkmcnt(0)" ::: "memory");
  __builtin_amdgcn_s_barrier();
  __builtin_amdgcn_sched_barrier(0);
}

#define WAIT_VM(N) asm volatile("s_waitcnt vmcnt(" #N ")" ::: "memory")

// Coherent (device-scope) loads/stores: sc0 sc1 -> data at coherence point.
// Loads are INVALID until a covering WAIT_VM.
__device__ __forceinline__ float ld_cohf(const float* p) {
  float v;
  asm volatile("global_load_dword %0, %1, off sc0 sc1" : "=v"(v) : "v"(p) : "memory");
  return v;
}
__device__ __forceinline__ int ld_cohi(const int* p) {
  int v;
  asm volatile("global_load_dword %0, %1, off sc0 sc1" : "=v"(v) : "v"(p) : "memory");
  return v;
}
__device__ __forceinline__ void st_cohf(float* p, float v) {
  asm volatile("global_store_dword %0, %1, off sc0 sc1" :: "v"(p), "v"(v) : "memory");
}
__device__ __forceinline__ void st_cohi(int* p, int v) {
  asm volatile("global_store_dword %0, %1, off sc0 sc1" :: "v"(p), "v"(v) : "memory");
}

// R15: strictly-static counted-vmcnt deep pipeline (R12/R13's bug was
// period-4 EXTRA ops breaking the count; here every phase issues an
// IDENTICAL op set, so the counts are exact at every phase).
//  b0: wv0-3 L0 cells | wv4 pub {S ring0, F flag0=t-7, C cons0-poll} = 3
//      ops/phase, WAIT_VM(20) at top (retires S(t-7): 2+3*6 newer ops)
//      | wv5 tbuf (own wave -> its loads can't perturb pub's counts).
//  b1: wv0-3 L1 cells | wv4 dma {L ring0 (dummy when closed), P flag0-poll,
//      C0 cons0-store} = 3 ops/phase, 8-slot rotation: load at p ->
//      LDS-commit at p+7 under WAIT_VM(20) (2+3*6 newer ops). 7-phase
//      flight ~4000cy >> cross-XCD RTT -> dma never stalls. Polls adopted
//      8 phases late (provably retired). | wv5 head (hid p-2 / out p-4 /
//      obuf windows, R10-verbatim). ring1/flag1/block2 DELETED.
// Cell/head math byte-identical to R7/R11/R14. setprio(1) on cells kept.
__global__ __launch_bounds__(384, 1) void decoder_p15(
    const float* __restrict__ h0in, const float* __restrict__ c0in,
    const float* __restrict__ diffp, const float* __restrict__ target,
    const float* __restrict__ Wih0, const float* __restrict__ Whh0,
    const float* __restrict__ bih0, const float* __restrict__ bhh0,
    const float* __restrict__ Wih1, const float* __restrict__ Whh1,
    const float* __restrict__ bih1, const float* __restrict__ bhh1,
    const float* __restrict__ Whid, const float* __restrict__ bhidp,
    const float* __restrict__ Woutp, const float* __restrict__ boutp,
    float* __restrict__ outp, float* __restrict__ ws, const int T)
{
  const int tid = threadIdx.x;
  const int wv  = tid >> 6;
  const int l   = tid & 63;
  const int q   = l >> 2;
  const int k   = l & 3;
  const int u   = 16 * (wv & 3) + q;
  const int r   = 64 * k + u;
  const bool isk0 = (k == 0);
  const float am = (k == 2) ? 2.0f : 1.0f;
  const float ab = (k == 2) ? -1.0f : 0.0f;

  __shared__ alignas(256) float h0r[4][64];        // b0
  __shared__ alignas(256) float tbuf[2][32 * NF];  // b0
  __shared__ alignas(256) float h0loc[16][64];     // b1
  __shared__ alignas(256) float h1r[4][64];        // b1
  __shared__ alignas(256) float hidS[4][32];       // b1 head
  __shared__ alignas(256) float obuf[64 * NF];     // b1 head
  __shared__ float ldspad[20480];                  // 80KB: 1 block/CU

  if (T < 0) {  // never true; keeps ldspad allocated
    ldspad[tid] = h0in[tid];
    __syncthreads();
    outp[0] = ldspad[383 - tid];
  }

  int* flag0p = (int*)ws;          // count of h0 steps durable in ring0
  int* cons0p = (int*)ws + 16;     // b1 dma fill progress (fillPub)
  float* ring0 = ws + 256;         // [RD][64]

  if (blockIdx.x == 0) {
    // ================= BLOCK 0 : layer 0 =================
    f2 wreg[36];
    float b_ = 0.f, xd = 0.f, cS = 0.f, hS = 0.f, xc = 0.f;
    if (wv < 4) {
      #pragma unroll
      for (int j = 0; j < 4; ++j) {
        const int row = 64 * ((k + j) & 3) + u;
        const float* rp = Whh0 + row * 64 + 16 * k;
        #pragma unroll
        for (int c = 0; c < 4; ++c) {
          f4 v = *(const f4*)(rp + 4 * ((c + k) & 3));
          wreg[8 * j + 2 * c]     = v.lo;
          wreg[8 * j + 2 * c + 1] = v.hi;
        }
      }
      b_ = bih0[r] + bhh0[r];
      const float* ra = Wih0 + r * 14;
      #pragma unroll
      for (int c = 0; c < 4; ++c) wreg[32 + c] = (f2){ra[2 * c], ra[2 * c + 1]};
      #pragma unroll
      for (int m = 0; m < 6; ++m) xd += ra[8 + m] * diffp[m];
      if (isk0) cS = c0in[u];
      if (wv == 0) h0r[3][l] = h0in[l];
    } else if (wv == 5) {
      if (l < T) {  // seed tbuf rows 0..63 (both buffers)
        *(f4*)&((float*)tbuf)[l * 8]     = *(const f4*)&target[l * 8];
        *(f4*)&((float*)tbuf)[l * 8 + 4] = *(const f4*)&target[l * 8 + 4];
      }
    }
    __syncthreads();
    if (wv < 4) __builtin_amdgcn_s_setprio(1);

    // pub state: 8-slot cons0 poll rotation
    int cpol[8];
    #pragma unroll
    for (int ii = 0; ii < 8; ++ii) cpol[ii] = 0;
    int cons0L = 0;
    f4 tr0 = {0.f, 0.f, 0.f, 0.f}, tr1 = {0.f, 0.f, 0.f, 0.f};

    for (int t = 0; t <= T; ++t) {
      if (wv < 4) {
        if (t < T) {
          const float* base = &h0r[(t - 1) & 3][16 * k];
          f2 P0 = {0.f,0.f}, P1 = {0.f,0.f}, P2 = {0.f,0.f}, P3 = {0.f,0.f};
          #pragma unroll
          for (int c = 0; c < 4; ++c) {
            f4 v = *(const f4*)(base + 4 * ((c + k) & 3));
            P0 += wreg[2*c] * v.lo;      P0 += wreg[2*c+1] * v.hi;
            P1 += wreg[8+2*c] * v.lo;    P1 += wreg[8+2*c+1] * v.hi;
            P2 += wreg[16+2*c] * v.lo;   P2 += wreg[16+2*c+1] * v.hi;
            P3 += wreg[24+2*c] * v.lo;   P3 += wreg[24+2*c+1] * v.hi;
          }
          float p0 = P0.x + P0.y, p1 = P1.x + P1.y;
          float p2 = P2.x + P2.y, p3 = P3.x + P3.y;
          float g = ((p0 + qp<0x39>(p3)) + (qp<0x4E>(p2) + qp<0x93>(p1))) + b_ + xc;
          float e = __expf(-g * am);
          float s = __fdividef(1.0f, 1.0f + e);
          float a = fmaf(s, am, ab);
          float A1 = qp<0xB1>(a), A2 = qp<0x4E>(a), A3 = qp<0x1B>(a);
          if (isk0) {
            cS = A1 * cS + a * A2;
            float e2 = __expf(-2.0f * cS);
            hS = A3 * (__fdividef(2.0f, 1.0f + e2) - 1.0f);
            h0r[t & 3][u] = hS;
          }
        }
        if (t < T - 1) {
          const f4* trow = (const f4*)&tbuf[(t >> 5) & 1][(t & 31) * NF];
          f4 r0 = trow[0], r1 = trow[1];
          f2 s2 = wreg[32] * r0.lo; s2 += wreg[33] * r0.hi;
          s2 += wreg[34] * r1.lo;   s2 += wreg[35] * r1.hi;
          xc = xd + s2.x + s2.y;
        } else xc = 0.f;
      } else if (wv == 4) {
        // -------- pub: static {S, F, C} per phase --------
        if (t < 16) { WAIT_VM(0); } else { WAIT_VM(20); }
        const int i8 = t & 7;
        #pragma unroll
        for (int ii = 0; ii < 8; ++ii) if (ii == i8) {
          if (cpol[ii] > cons0L) cons0L = cpol[ii];   // adopt t-8 value
        }
        if (t - cons0L > RD - 64) {   // backpressure (rare; self-healing)
          WAIT_VM(0);
          while (t - cons0L > RD - 64) {
            cons0L = ld_cohi(cons0p);
            WAIT_VM(0);
          }
        }
        if (t >= 1) {
          float hv = h0r[(t - 1) & 3][l];
          st_cohf(&ring0[((t - 1) & RMASK) * 64 + l], hv);   // S
        }
        {
          int fv = t - 7; if (fv < 0) fv = 0;
          if (l == 0) st_cohi(flag0p, fv);                    // F
        }
        #pragma unroll
        for (int ii = 0; ii < 8; ++ii) if (ii == i8)
          cpol[ii] = ld_cohi(cons0p);                         // C
      } else {
        // -------- tbuf wave: loads ph8, writes ph26 (private waits) ----
        const int ph = t & 31;
        const int cl = (t >> 5) + 1;
        if (l < 32 && cl * 32 < T) {
          if (ph == 8) {
            tr0 = *(const f4*)&target[cl * 256 + l * 8];
            tr1 = *(const f4*)&target[cl * 256 + l * 8 + 4];
          } else if (ph == 26) {
            WAIT_VM(0);
            *(f4*)&tbuf[cl & 1][l * 8]     = tr0;
            *(f4*)&tbuf[cl & 1][l * 8 + 4] = tr1;
          }
        }
      }
      wg_barrier();
    }
    if (wv == 4) {
      WAIT_VM(0);
      if (l == 0) st_cohi(flag0p, T);   // final release
    }
    if (wv < 4 && isk0) {
      outp[T * NF + u]       = hS;   // h_final layer 0
      outp[T * NF + 128 + u] = cS;   // c_final layer 0
    }
  } else {
    // ================= BLOCK 1 : layer 1 + head =================
    f2 wreg[64];
    f2 wH[16], wO[4];
    float b_ = 0.f, cS = 0.f, hS = 0.f;
    float bhA = 0.f, bhB = 0.f, bo_ = 0.f;
    if (wv < 4) {
      const float* Wsrc = (k < 2) ? Wih1 : Whh1;
      const int co = 32 * (k & 1);
      #pragma unroll
      for (int j = 0; j < 4; ++j) {
        const int row = 64 * ((k + j) & 3) + u;
        const float* rp = Wsrc + row * 64 + co;
        #pragma unroll
        for (int c = 0; c < 8; ++c) {
          f4 v = *(const f4*)(rp + 4 * ((c + 2 * k) & 7));
          wreg[16 * j + 2 * c]     = v.lo;
          wreg[16 * j + 2 * c + 1] = v.hi;
        }
      }
      b_ = bih1[r] + bhh1[r];
      if (isk0) cS = c0in[64 + u];
      if (wv == 0) h1r[3][l] = h0in[64 + l];
    } else if (wv == 5) {
      // head weights: R10-verbatim layouts
      #pragma unroll
      for (int i = 0; i < 2; ++i) {
        const float* rp = Whid + (2 * q + i) * 64 + 16 * k;
        #pragma unroll
        for (int c = 0; c < 4; ++c) {
          f4 v = *(const f4*)(rp + 4 * ((c + k) & 3));
          wH[8 * i + 2 * c]     = v.lo;
          wH[8 * i + 2 * c + 1] = v.hi;
        }
      }
      bhA = bhidp[2 * q];
      bhB = bhidp[2 * q + 1];
      if (q < 8) {
        const float* rp = Woutp + q * 32 + 8 * k;
        #pragma unroll
        for (int c = 0; c < 2; ++c) {
          f4 v = *(const f4*)(rp + 4 * ((c + k) & 1));
          wO[2 * c]     = v.lo;
          wO[2 * c + 1] = v.hi;
        }
        bo_ = boutp[q];
      }
    }
    // ---- dma state: 8-slot load rotation + 8-slot flag polls ----
    float pend[8];
    int ps[8], fpol[8];
    #pragma unroll
    for (int ii = 0; ii < 8; ++ii) { pend[ii] = 0.f; ps[ii] = -1; fpol[ii] = 0; }
    int flagL = 0, fillW = 0, fillPub = 0;
    if (wv == 4) {
      const int pf = (T < 16) ? T : 16;   // prefill (drained)
      while (flagL < pf) {
        flagL = ld_cohi(flag0p);
        WAIT_VM(0);
      }
      for (int s = 0; s < pf; ++s) {
        float v = ld_cohf(&ring0[(s & RMASK) * 64 + l]);
        WAIT_VM(0);
        h0loc[s & 15][l] = v;
      }
      fillW = pf;
      fillPub = pf;
    }
    __syncthreads();
    if (wv < 4) __builtin_amdgcn_s_setprio(1);

    const int pend_ = T + 4;
    for (int p = 0; p <= pend_; ++p) {
      if (wv < 4) {
        // -------- L1 cell: h1[p] = cell(h0[p], h1[p-1]) --------
        if (p < T) {
          const float* base = (k < 2) ? &h0loc[p & 15][32 * (k & 1)]
                                      : &h1r[(p - 1) & 3][32 * (k & 1)];
          f2 P0 = {0.f,0.f}, P1 = {0.f,0.f}, P2 = {0.f,0.f}, P3 = {0.f,0.f};
          #pragma unroll
          for (int c = 0; c < 8; ++c) {
            f4 v = *(const f4*)(base + 4 * ((c + 2 * k) & 7));
            P0 += wreg[2*c] * v.lo;      P0 += wreg[2*c+1] * v.hi;
            P1 += wreg[16+2*c] * v.lo;   P1 += wreg[16+2*c+1] * v.hi;
            P2 += wreg[32+2*c] * v.lo;   P2 += wreg[32+2*c+1] * v.hi;
            P3 += wreg[48+2*c] * v.lo;   P3 += wreg[48+2*c+1] * v.hi;
          }
          float p0 = P0.x + P0.y, p1 = P1.x + P1.y;
          float p2 = P2.x + P2.y, p3 = P3.x + P3.y;
          float g = ((p0 + qp<0x39>(p3)) + (qp<0x4E>(p2) + qp<0x93>(p1))) + b_;
          float e = __expf(-g * am);
          float s = __fdividef(1.0f, 1.0f + e);
          float a = fmaf(s, am, ab);
          float A1 = qp<0xB1>(a), A2 = qp<0x4E>(a), A3 = qp<0x1B>(a);
          if (isk0) {
            cS = A1 * cS + a * A2;
            float e2 = __expf(-2.0f * cS);
            hS = A3 * (__fdividef(2.0f, 1.0f + e2) - 1.0f);
            h1r[p & 3][u] = hS;
          }
        }
      } else if (wv == 4) {
        // -------- dma: static {L, P, C0} per phase, 7-phase flight -------
        if (p < 8) { WAIT_VM(0); } else { WAIT_VM(20); }
        const int i8 = p & 7;
        const int wr = (i8 + 1) & 7;     // slot loaded at p-7
        #pragma unroll
        for (int ii = 0; ii < 8; ++ii) if (ii == wr) {
          if (ps[ii] >= 0) {
            h0loc[ps[ii] & 15][l] = pend[ii];
            if (ps[ii] + 1 > fillPub) fillPub = ps[ii] + 1;
            ps[ii] = -1;
          }
        }
        #pragma unroll
        for (int ii = 0; ii < 8; ++ii) if (ii == i8) {
          if (fpol[ii] > flagL) flagL = fpol[ii];   // adopt p-8 poll
        }
        // ---- emergency: ensure steps <= min(p+2,T) present (rare) ----
        if (fillPub < p + 2 && fillPub < T) {
          WAIT_VM(0);
          #pragma unroll
          for (int ii = 0; ii < 8; ++ii) {
            if (ps[ii] >= 0) {
              h0loc[ps[ii] & 15][l] = pend[ii];
              if (ps[ii] + 1 > fillPub) fillPub = ps[ii] + 1;
              ps[ii] = -1;
            }
          }
          if (fillW < fillPub) fillW = fillPub;
          int need = p + 8; if (need > T) need = T;
          while (fillPub < need) {
            while (flagL < fillPub + 1) {
              flagL = ld_cohi(flag0p);
              WAIT_VM(0);
            }
            float v = ld_cohf(&ring0[(fillPub & RMASK) * 64 + l]);
            WAIT_VM(0);
            h0loc[fillPub & 15][l] = v;
            ++fillPub;
          }
          if (fillW < fillPub) fillW = fillPub;
        }
        // ---- L: exactly one ring0 load (dummy keeps count static) ----
        {
          int cap = p + 20;              // write at p+7; slot-conflict-safe
          if (cap > flagL) cap = flagL;
          if (cap > T) cap = T;
          const bool ok = (fillW < cap);
          const float* ap = ok ? &ring0[(fillW & RMASK) * 64 + l] : &ring0[l];
          #pragma unroll
          for (int ii = 0; ii < 8; ++ii) if (ii == i8) {
            pend[ii] = ld_cohf(ap);
            ps[ii] = ok ? fillW : -1;
          }
          if (ok) ++fillW;
        }
        #pragma unroll
        for (int ii = 0; ii < 8; ++ii) if (ii == i8)
          fpol[ii] = ld_cohi(flag0p);                       // P
        if (l == 0) st_cohi(cons0p, fillPub);               // C0
      } else {
        // -------- head (wv5): hid[p-2], out[p-4], windowed stores -------
        const int sH = p - 2;
        if (sH >= 0 && sH < T) {
          const float* hp = &h1r[sH & 3][16 * k];
          f2 pa = {0.f,0.f}, pb = {0.f,0.f};
          #pragma unroll
          for (int c = 0; c < 4; ++c) {
            f4 v = *(const f4*)(hp + 4 * ((c + k) & 3));
            pa += wH[2*c] * v.lo;     pa += wH[2*c+1] * v.hi;
            pb += wH[8+2*c] * v.lo;   pb += wH[8+2*c+1] * v.hi;
          }
          float sa = pa.x + pa.y; sa += qp<0xB1>(sa); sa += qp<0x4E>(sa);
          float sb = pb.x + pb.y; sb += qp<0xB1>(sb); sb += qp<0x4E>(sb);
          if (isk0) *(f2*)&hidS[sH & 3][2 * q] = (f2){sa + bhA, sb + bhB};
        }
        const int sO = p - 4;
        if (sO >= 0 && sO < T && q < 8) {
          const float* hp = &hidS[sO & 3][8 * k];
          f2 po = {0.f,0.f};
          #pragma unroll
          for (int c = 0; c < 2; ++c) {
            f4 v = *(const f4*)(hp + 4 * ((c + k) & 1));
            po += wO[2*c] * v.lo; po += wO[2*c+1] * v.hi;
          }
          float so = po.x + po.y; so += qp<0xB1>(so); so += qp<0x4E>(so);
          if (isk0) obuf[(sO & 63) * NF + q] = rintf(so + bo_);
        }
        if (l >= 32 && (p & 31) == 5 && p >= 37) {
          const int j = l - 32;
          #pragma unroll
          for (int ii = 0; ii < 2; ++ii) {
            const int fidx = 2 * j + ii;
            const int s  = (p - 37) + (fidx >> 1);
            const int c4 = (fidx & 1) * 4;
            *(f4*)&outp[s * NF + c4] = *(const f4*)&obuf[(s & 63) * NF + c4];
          }
        }
      }
      wg_barrier();
    }
    if (wv < 4 && isk0) {
      outp[T * NF + 64 + u]  = hS;   // h_final layer 1
      outp[T * NF + 192 + u] = cS;   // c_final layer 1
    }
    __syncthreads();
    {
      int s0 = T - 64;
      if (s0 < 0) s0 = 0;
      for (int idx = tid; idx < (T - s0) * NF; idx += 384) {
        const int s = s0 + (idx >> 3);
        outp[s * NF + (idx & 7)] = obuf[(s & 63) * NF + (idx & 7)];
      }
    }
  }
}

extern "C" void kernel_launch(void* const* d_in, const int* in_sizes, int n_in,
                              void* d_out, int out_size, void* d_ws, size_t ws_size,
                              hipStream_t stream) {
  const float* h0in   = (const float*)d_in[1];
  const float* c0in   = (const float*)d_in[2];
  const float* diffp  = (const float*)d_in[3];
  const float* target = (const float*)d_in[4];
  const float* Wih0   = (const float*)d_in[5];
  const float* Whh0   = (const float*)d_in[6];
  const float* bih0   = (const float*)d_in[7];
  const float* bhh0   = (const float*)d_in[8];
  const float* Wih1   = (const float*)d_in[9];
  const float* Whh1   = (const float*)d_in[10];
  const float* bih1   = (const float*)d_in[11];
  const float* bhh1   = (const float*)d_in[12];
  const float* Whid   = (const float*)d_in[13];
  const float* bhidp  = (const float*)d_in[14];
  const float* Woutp  = (const float*)d_in[15];
  const float* boutp  = (const float*)d_in[16];
  float* outp = (float*)d_out;
  const int T = in_sizes[4] / NF;

  hipMemsetAsync(d_ws, 0, 256, stream);   // zero flags (graph-capturable)
  decoder_p15<<<dim3(2), dim3(384), 0, stream>>>(
      h0in, c0in, diffp, target,
      Wih0, Whh0, bih0, bhh0,
      Wih1, Whh1, bih1, bhh1,
      Whid, bhidp, Woutp, boutp,
      outp, (float*)d_ws, T);
}

// Round 11
// 9878.120 us; speedup vs baseline: 1.5438x; 1.5438x over previous
//
#include <hip/hip_runtime.h>

#define NF 8
#define RMASK 255
#define SENT 0xFFFFFFFFu

typedef float f2 __attribute__((ext_vector_type(2)));
typedef float f4 __attribute__((ext_vector_type(4)));

template <int CTRL>
__device__ __forceinline__ float qp(float x) {
  return __int_as_float(
      __builtin_amdgcn_update_dpp(0, __float_as_int(x), CTRL, 0xF, 0xF, true));
}

// Raw barrier: LDS-ordering only (global ops stay in flight across phases).
__device__ __forceinline__ void wg_barrier() {
  asm volatile("s_waitcnt lgkmcnt(0)" ::: "memory");
  __builtin_amdgcn_s_barrier();
  __builtin_amdgcn_sched_barrier(0);
}

#define WAIT_VM(N) asm volatile("s_waitcnt vmcnt(" #N ")" ::: "memory")

// Coherent (device-scope) ops: sc0 sc1 -> to/from the coherence point.
__device__ __forceinline__ float ld_cohf(const float* p) {
  float v;
  asm volatile("global_load_dword %0, %1, off sc0 sc1" : "=v"(v) : "v"(p) : "memory");
  return v;
}
__device__ __forceinline__ int ld_cohi(const int* p) {
  int v;
  asm volatile("global_load_dword %0, %1, off sc0 sc1" : "=v"(v) : "v"(p) : "memory");
  return v;
}
__device__ __forceinline__ void st_cohf(float* p, float v) {
  asm volatile("global_store_dword %0, %1, off sc0 sc1" :: "v"(p), "v"(v) : "memory");
}
__device__ __forceinline__ void st_cohi(int* p, int v) {
  asm volatile("global_store_dword %0, %1, off sc0 sc1" :: "v"(p), "v"(v) : "memory");
}

// R18: flag-free sentinel transport. d_ws ring is pre-poisoned 0xFFFFFFFF
// (NaN; |h0|<1 so never legit). Slot = step (NO reuse, ~5.2MB) -> b0 pub is
// a bare coherent-store stream with ZERO polls/flags -> b0 can never block
// -> deadlock-free by construction. b1 dma speculatively ld_cohf's the next
// <=4 slots each phase (1-phase pending registers - the ONLY depth that has
// ever passed: R11/R14), WAIT_VM(0) at top (~free, loads a full phase old),
// commits the all-lanes-non-sentinel prefix to LDS, retries the rest.
// Validity is in the data itself: no op-counted vmcnt anywhere (all waits
// VM(0)), no flag line, no global_load_lds, no unverified encodings.
// Head in b1 wv5 (R15-verbatim, passed); ring1/b2 deleted. Cell math
// byte-identical R14. Fallback (small ws): R14's flag+backpressure dma.
__global__ __launch_bounds__(384, 1) void decoder_p18(
    const float* __restrict__ h0in, const float* __restrict__ c0in,
    const float* __restrict__ diffp, const float* __restrict__ target,
    const float* __restrict__ Wih0, const float* __restrict__ Whh0,
    const float* __restrict__ bih0, const float* __restrict__ bhh0,
    const float* __restrict__ Wih1, const float* __restrict__ Whh1,
    const float* __restrict__ bih1, const float* __restrict__ bhh1,
    const float* __restrict__ Whid, const float* __restrict__ bhidp,
    const float* __restrict__ Woutp, const float* __restrict__ boutp,
    float* __restrict__ outp, float* __restrict__ ws, const int T,
    const int BP)
{
  const int tid = threadIdx.x;
  const int wv  = tid >> 6;
  const int l   = tid & 63;
  const int q   = l >> 2;
  const int k   = l & 3;
  const int u   = 16 * (wv & 3) + q;
  const int r   = 64 * k + u;
  const bool isk0 = (k == 0);
  const float am = (k == 2) ? 2.0f : 1.0f;
  const float ab = (k == 2) ? -1.0f : 0.0f;

  __shared__ alignas(256) float h0r[4][64];        // b0
  __shared__ alignas(256) float tbuf[2][32 * NF];  // b0
  __shared__ alignas(256) float h0loc[16][64];     // b1
  __shared__ alignas(256) float h1r[4][64];        // b1
  __shared__ alignas(256) float hidS[4][32];       // b1
  __shared__ alignas(256) float obuf[64 * NF];     // b1
  __shared__ float ldspad[20480];                  // 80KB: 1 block/CU

  if (T < 0) {  // never true; keeps ldspad allocated
    ldspad[tid] = h0in[tid];
    __syncthreads();
    outp[0] = ldspad[383 - tid];
  }

  int* flag0p = (int*)ws;          // BP mode only (line A)
  int* cons0p = (int*)ws + 64;     // BP mode only (line B)
  float* ring0 = ws + 256;         // slot=step (BP=0) or slot=step&255 (BP=1)

  if (blockIdx.x == 0) {
    // ================= BLOCK 0 : layer 0 =================
    f2 wreg[36];
    float b_ = 0.f, xd = 0.f, cS = 0.f, hS = 0.f, xc = 0.f;
    if (wv < 4) {
      #pragma unroll
      for (int j = 0; j < 4; ++j) {
        const int row = 64 * ((k + j) & 3) + u;
        const float* rp = Whh0 + row * 64 + 16 * k;
        #pragma unroll
        for (int c = 0; c < 4; ++c) {
          f4 v = *(const f4*)(rp + 4 * ((c + k) & 3));
          wreg[8 * j + 2 * c]     = v.lo;
          wreg[8 * j + 2 * c + 1] = v.hi;
        }
      }
      b_ = bih0[r] + bhh0[r];
      const float* ra = Wih0 + r * 14;
      #pragma unroll
      for (int c = 0; c < 4; ++c) wreg[32 + c] = (f2){ra[2 * c], ra[2 * c + 1]};
      #pragma unroll
      for (int m = 0; m < 6; ++m) xd += ra[8 + m] * diffp[m];
      if (isk0) cS = c0in[u];
      if (wv == 0) h0r[3][l] = h0in[l];
    } else if (wv == 5) {
      if (l < T) {  // seed tbuf rows 0..63 (both buffers)
        *(f4*)&((float*)tbuf)[l * 8]     = *(const f4*)&target[l * 8];
        *(f4*)&((float*)tbuf)[l * 8 + 4] = *(const f4*)&target[l * 8 + 4];
      }
    }
    __syncthreads();
    if (wv < 4) __builtin_amdgcn_s_setprio(1);

    int cons0L = 0;
    f4 tr0 = {0.f, 0.f, 0.f, 0.f}, tr1 = {0.f, 0.f, 0.f, 0.f};
    for (int t = 0; t <= T; ++t) {
      if (wv < 4) {
        if (t < T) {
          const float* base = &h0r[(t - 1) & 3][16 * k];
          f2 P0 = {0.f,0.f}, P1 = {0.f,0.f}, P2 = {0.f,0.f}, P3 = {0.f,0.f};
          #pragma unroll
          for (int c = 0; c < 4; ++c) {
            f4 v = *(const f4*)(base + 4 * ((c + k) & 3));
            P0 += wreg[2*c] * v.lo;      P0 += wreg[2*c+1] * v.hi;
            P1 += wreg[8+2*c] * v.lo;    P1 += wreg[8+2*c+1] * v.hi;
            P2 += wreg[16+2*c] * v.lo;   P2 += wreg[16+2*c+1] * v.hi;
            P3 += wreg[24+2*c] * v.lo;   P3 += wreg[24+2*c+1] * v.hi;
          }
          float p0 = P0.x + P0.y, p1 = P1.x + P1.y;
          float p2 = P2.x + P2.y, p3 = P3.x + P3.y;
          float g = ((p0 + qp<0x39>(p3)) + (qp<0x4E>(p2) + qp<0x93>(p1))) + b_ + xc;
          float e = __expf(-g * am);
          float s = __fdividef(1.0f, 1.0f + e);
          float a = fmaf(s, am, ab);
          float A1 = qp<0xB1>(a), A2 = qp<0x4E>(a), A3 = qp<0x1B>(a);
          if (isk0) {
            cS = A1 * cS + a * A2;
            float e2 = __expf(-2.0f * cS);
            hS = A3 * (__fdividef(2.0f, 1.0f + e2) - 1.0f);
            h0r[t & 3][u] = hS;
          }
        }
        if (t < T - 1) {
          const f4* trow = (const f4*)&tbuf[(t >> 5) & 1][(t & 31) * NF];
          f4 r0 = trow[0], r1 = trow[1];
          f2 s2 = wreg[32] * r0.lo; s2 += wreg[33] * r0.hi;
          s2 += wreg[34] * r1.lo;   s2 += wreg[35] * r1.hi;
          xc = xd + s2.x + s2.y;
        } else xc = 0.f;
      } else if (wv == 4) {
        if (!BP) {
          // ---- primary pub: bare store stream; never blocks ----
          if (t >= 1) {
            float hv = h0r[(t - 1) & 3][l];
            st_cohf(&ring0[(t - 1) * 64 + l], hv);
          }
        } else {
          // ---- BP pub (R14-verbatim counts, tbuf removed) ----
          if ((t & 3) == 0 && t >= 8) {
            WAIT_VM(4);   // S(t-7) has 6 newer ops -> retired
            if (l == 0) st_cohi(flag0p, t - 6);
          }
          if ((t & 63) == 0 && t > 192) {
            while (t - cons0L > 192) {
              cons0L = ld_cohi(cons0p);
              WAIT_VM(0);
            }
          }
          if (t >= 1) {
            float hv = h0r[(t - 1) & 3][l];
            st_cohf(&ring0[((t - 1) & RMASK) * 64 + l], hv);
          }
        }
      } else {
        // ---- tbuf wave: loads ph8, writes ph26 (own vmcnt domain) ----
        const int ph = t & 31;
        const int cl = (t >> 5) + 1;
        if (l < 32 && cl * 32 < T) {
          if (ph == 8) {
            tr0 = *(const f4*)&target[cl * 256 + l * 8];
            tr1 = *(const f4*)&target[cl * 256 + l * 8 + 4];
          } else if (ph == 26) {
            WAIT_VM(0);
            *(f4*)&tbuf[cl & 1][l * 8]     = tr0;
            *(f4*)&tbuf[cl & 1][l * 8 + 4] = tr1;
          }
        }
      }
      wg_barrier();
    }
    if (BP && wv == 4) {
      WAIT_VM(0);
      if (l == 0) st_cohi(flag0p, T);
    }
    if (wv < 4 && isk0) {
      outp[T * NF + u]       = hS;   // h_final layer 0
      outp[T * NF + 128 + u] = cS;   // c_final layer 0
    }
  } else {
    // ================= BLOCK 1 : layer 1 + dma + head =================
    f2 wreg[64];
    f2 wH[16], wO[4];
    float b_ = 0.f, cS = 0.f, hS = 0.f;
    float bhA = 0.f, bhB = 0.f, bo_ = 0.f;
    if (wv < 4) {
      const float* Wsrc = (k < 2) ? Wih1 : Whh1;
      const int co = 32 * (k & 1);
      #pragma unroll
      for (int j = 0; j < 4; ++j) {
        const int row = 64 * ((k + j) & 3) + u;
        const float* rp = Wsrc + row * 64 + co;
        #pragma unroll
        for (int c = 0; c < 8; ++c) {
          f4 v = *(const f4*)(rp + 4 * ((c + 2 * k) & 7));
          wreg[16 * j + 2 * c]     = v.lo;
          wreg[16 * j + 2 * c + 1] = v.hi;
        }
      }
      b_ = bih1[r] + bhh1[r];
      if (isk0) cS = c0in[64 + u];
      if (wv == 0) h1r[3][l] = h0in[64 + l];
    } else if (wv == 5) {
      // head weights (R15-verbatim layouts)
      #pragma unroll
      for (int i = 0; i < 2; ++i) {
        const float* rp = Whid + (2 * q + i) * 64 + 16 * k;
        #pragma unroll
        for (int c = 0; c < 4; ++c) {
          f4 v = *(const f4*)(rp + 4 * ((c + k) & 3));
          wH[8 * i + 2 * c]     = v.lo;
          wH[8 * i + 2 * c + 1] = v.hi;
        }
      }
      bhA = bhidp[2 * q];
      bhB = bhidp[2 * q + 1];
      if (q < 8) {
        const float* rp = Woutp + q * 32 + 8 * k;
        #pragma unroll
        for (int c = 0; c < 2; ++c) {
          f4 v = *(const f4*)(rp + 4 * ((c + k) & 1));
          wO[2 * c]     = v.lo;
          wO[2 * c + 1] = v.hi;
        }
        bo_ = boutp[q];
      }
    }
    __syncthreads();

    // ---- dma prologue ----
    float pb0 = 0.f, pb1 = 0.f, pb2 = 0.f, pb3 = 0.f;
    int ns = 0, fillW = 0, flagL = 0, F_pend = 0, nPend = 0;
    if (wv == 4) {
      if (!BP) {
        const int pf = (T < 8) ? T : 8;   // sentinel-poll prefill
        while (fillW < pf) {
          float v = ld_cohf(&ring0[fillW * 64 + l]);
          WAIT_VM(0);
          if (__all(__float_as_uint(v) != SENT)) {
            h0loc[fillW & 15][l] = v;
            ++fillW;
          }
        }
      } else {
        const int pf = (T < 4) ? T : 4;   // flag-gated prefill (R14)
        while (flagL < pf) {
          flagL = ld_cohi(flag0p);
          WAIT_VM(0);
        }
        for (int s = 0; s < pf; ++s) {
          float v = ld_cohf(&ring0[(s & RMASK) * 64 + l]);
          WAIT_VM(0);
          h0loc[s & 15][l] = v;
        }
        fillW = pf;
        F_pend = flagL;
      }
    }
    __syncthreads();
    if (wv < 4) __builtin_amdgcn_s_setprio(1);

    const int pend_ = T + 4;
    for (int p = 0; p <= pend_; ++p) {
      if (wv < 4) {
        // -------- L1 cell (R14-verbatim; zero vmem) --------
        if (p < T) {
          const float* base = (k < 2) ? &h0loc[p & 15][32 * (k & 1)]
                                      : &h1r[(p - 1) & 3][32 * (k & 1)];
          f2 P0 = {0.f,0.f}, P1 = {0.f,0.f}, P2 = {0.f,0.f}, P3 = {0.f,0.f};
          #pragma unroll
          for (int c = 0; c < 8; ++c) {
            f4 v = *(const f4*)(base + 4 * ((c + 2 * k) & 7));
            P0 += wreg[2*c] * v.lo;      P0 += wreg[2*c+1] * v.hi;
            P1 += wreg[16+2*c] * v.lo;   P1 += wreg[16+2*c+1] * v.hi;
            P2 += wreg[32+2*c] * v.lo;   P2 += wreg[32+2*c+1] * v.hi;
            P3 += wreg[48+2*c] * v.lo;   P3 += wreg[48+2*c+1] * v.hi;
          }
          float p0 = P0.x + P0.y, p1 = P1.x + P1.y;
          float p2 = P2.x + P2.y, p3 = P3.x + P3.y;
          float g = ((p0 + qp<0x39>(p3)) + (qp<0x4E>(p2) + qp<0x93>(p1))) + b_;
          float e = __expf(-g * am);
          float s = __fdividef(1.0f, 1.0f + e);
          float a = fmaf(s, am, ab);
          float A1 = qp<0xB1>(a), A2 = qp<0x4E>(a), A3 = qp<0x1B>(a);
          if (isk0) {
            cS = A1 * cS + a * A2;
            float e2 = __expf(-2.0f * cS);
            hS = A3 * (__fdividef(2.0f, 1.0f + e2) - 1.0f);
            h1r[p & 3][u] = hS;
          }
        }
      } else if (wv == 4) {
        if (!BP) {
          // ---- primary dma: sentinel ring, all waits VM(0) ----
          WAIT_VM(0);   // pends issued last phase: ~1 phase old, ~free
          // commit valid prefix (partial visibility -> per-lane check)
          bool stop = false;
          if (ns > 0 && !stop) {
            if (__all(__float_as_uint(pb0) != SENT)) { h0loc[fillW & 15][l] = pb0; ++fillW; }
            else stop = true;
          }
          if (ns > 1 && !stop) {
            if (__all(__float_as_uint(pb1) != SENT)) { h0loc[fillW & 15][l] = pb1; ++fillW; }
            else stop = true;
          }
          if (ns > 2 && !stop) {
            if (__all(__float_as_uint(pb2) != SENT)) { h0loc[fillW & 15][l] = pb2; ++fillW; }
            else stop = true;
          }
          if (ns > 3 && !stop) {
            if (__all(__float_as_uint(pb3) != SENT)) { h0loc[fillW & 15][l] = pb3; ++fillW; }
            else stop = true;
          }
          ns = 0;
          // emergency: cells at p+1 need step p+1 (blocking poll; b0 free-runs)
          {
            int lim = p + 2; if (lim > T) lim = T;
            while (fillW < lim) {
              float v = ld_cohf(&ring0[fillW * 64 + l]);
              WAIT_VM(0);
              if (__all(__float_as_uint(v) != SENT)) {
                h0loc[fillW & 15][l] = v;
                ++fillW;
              }
            }
          }
          // speculative issue (<=4; cap p+14 keeps LDS ring safe)
          {
            int want = p + 14; if (want > T) want = T;
            int n = want - fillW; if (n < 0) n = 0; if (n > 4) n = 4;
            if (n > 0) pb0 = ld_cohf(&ring0[(fillW + 0) * 64 + l]);
            if (n > 1) pb1 = ld_cohf(&ring0[(fillW + 1) * 64 + l]);
            if (n > 2) pb2 = ld_cohf(&ring0[(fillW + 2) * 64 + l]);
            if (n > 3) pb3 = ld_cohf(&ring0[(fillW + 3) * 64 + l]);
            ns = n;
          }
        } else {
          // ---- BP dma (R14-verbatim minus ring1; all top-waits VM(0)) ----
          WAIT_VM(0);
          if (nPend > 0) h0loc[(fillW + 0) & 15][l] = pb0;
          if (nPend > 1) h0loc[(fillW + 1) & 15][l] = pb1;
          if (nPend > 2) h0loc[(fillW + 2) & 15][l] = pb2;
          if (nPend > 3) h0loc[(fillW + 3) & 15][l] = pb3;
          fillW += nPend;
          nPend = 0;
          if ((p & 3) == 1) flagL = F_pend;
          {  // emergency
            int need = p + 2; if (need > T) need = T;
            while (fillW < need) {
              while (flagL < fillW + 1) {
                flagL = ld_cohi(flag0p);
                WAIT_VM(0);
              }
              float v = ld_cohf(&ring0[(fillW & RMASK) * 64 + l]);
              WAIT_VM(0);
              h0loc[fillW & 15][l] = v;
              ++fillW;
            }
          }
          if ((p & 3) == 0) F_pend = ld_cohi(flag0p);  // adopt at p+1 (drained)
          {
            int want = flagL;
            if (want > p + 10) want = p + 10;
            if (want > T) want = T;
            int n = want - fillW;
            if (n < 0) n = 0;
            if (n > 4) n = 4;
            if (n > 0) pb0 = ld_cohf(&ring0[((fillW + 0) & RMASK) * 64 + l]);
            if (n > 1) pb1 = ld_cohf(&ring0[((fillW + 1) & RMASK) * 64 + l]);
            if (n > 2) pb2 = ld_cohf(&ring0[((fillW + 2) & RMASK) * 64 + l]);
            if (n > 3) pb3 = ld_cohf(&ring0[((fillW + 3) & RMASK) * 64 + l]);
            nPend = n;
          }
          if ((p & 63) == 32 && l == 0) st_cohi(cons0p, fillW);
        }
      } else {
        // -------- head (R15-verbatim): hid[p-2], out[p-4], stores -------
        const int sH = p - 2;
        if (sH >= 0 && sH < T) {
          const float* hp = &h1r[sH & 3][16 * k];
          f2 pa = {0.f,0.f}, pb = {0.f,0.f};
          #pragma unroll
          for (int c = 0; c < 4; ++c) {
            f4 v = *(const f4*)(hp + 4 * ((c + k) & 3));
            pa += wH[2*c] * v.lo;     pa += wH[2*c+1] * v.hi;
            pb += wH[8+2*c] * v.lo;   pb += wH[8+2*c+1] * v.hi;
          }
          float sa = pa.x + pa.y; sa += qp<0xB1>(sa); sa += qp<0x4E>(sa);
          float sb = pb.x + pb.y; sb += qp<0xB1>(sb); sb += qp<0x4E>(sb);
          if (isk0) *(f2*)&hidS[sH & 3][2 * q] = (f2){sa + bhA, sb + bhB};
        }
        const int sO = p - 4;
        if (sO >= 0 && sO < T && q < 8) {
          const float* hp = &hidS[sO & 3][8 * k];
          f2 po = {0.f,0.f};
          #pragma unroll
          for (int c = 0; c < 2; ++c) {
            f4 v = *(const f4*)(hp + 4 * ((c + k) & 1));
            po += wO[2*c] * v.lo; po += wO[2*c+1] * v.hi;
          }
          float so = po.x + po.y; so += qp<0xB1>(so); so += qp<0x4E>(so);
          if (isk0) obuf[(sO & 63) * NF + q] = rintf(so + bo_);
        }
        if (l >= 32 && (p & 31) == 5 && p >= 37) {
          const int j = l - 32;
          #pragma unroll
          for (int ii = 0; ii < 2; ++ii) {
            const int fidx = 2 * j + ii;
            const int s  = (p - 37) + (fidx >> 1);
            const int c4 = (fidx & 1) * 4;
            *(f4*)&outp[s * NF + c4] = *(const f4*)&obuf[(s & 63) * NF + c4];
          }
        }
      }
      wg_barrier();
    }
    if (wv < 4 && isk0) {
      outp[T * NF + 64 + u]  = hS;   // h_final layer 1
      outp[T * NF + 192 + u] = cS;   // c_final layer 1
    }
    __syncthreads();
    {
      int s0 = T - 64;
      if (s0 < 0) s0 = 0;
      for (int idx = tid; idx < (T - s0) * NF; idx += 384) {
        const int s = s0 + (idx >> 3);
        outp[s * NF + (idx & 7)] = obuf[(s & 63) * NF + (idx & 7)];
      }
    }
  }
}

extern "C" void kernel_launch(void* const* d_in, const int* in_sizes, int n_in,
                              void* d_out, int out_size, void* d_ws, size_t ws_size,
                              hipStream_t stream) {
  const float* h0in   = (const float*)d_in[1];
  const float* c0in   = (const float*)d_in[2];
  const float* diffp  = (const float*)d_in[3];
  const float* target = (const float*)d_in[4];
  const float* Wih0   = (const float*)d_in[5];
  const float* Whh0   = (const float*)d_in[6];
  const float* bih0   = (const float*)d_in[7];
  const float* bhh0   = (const float*)d_in[8];
  const float* Wih1   = (const float*)d_in[9];
  const float* Whh1   = (const float*)d_in[10];
  const float* bih1   = (const float*)d_in[11];
  const float* bhh1   = (const float*)d_in[12];
  const float* Whid   = (const float*)d_in[13];
  const float* bhidp  = (const float*)d_in[14];
  const float* Woutp  = (const float*)d_in[15];
  const float* boutp  = (const float*)d_in[16];
  float* outp = (float*)d_out;
  const int T = in_sizes[4] / NF;

  // Primary: no-reuse sentinel ring (needs ~5.2MB). Fallback: R14 protocol.
  const size_t need = ((size_t)256 + (size_t)T * 64) * 4;
  int BP;
  if (ws_size >= need) {
    BP = 0;
    hipMemsetAsync(d_ws, 0xFF, need, stream);   // poison ring with NaN sentinel
  } else {
    BP = 1;
    hipMemsetAsync(d_ws, 0, 1024, stream);      // zero flag + cons lines
  }

  decoder_p18<<<dim3(2), dim3(384), 0, stream>>>(
      h0in, c0in, diffp, target,
      Wih0, Whh0, bih0, bhh0,
      Wih1, Whh1, bih1, bhh1,
      Whid, bhidp, Woutp, boutp,
      outp, (float*)d_ws, T, BP);
}

// Round 13
// 9789.695 us; speedup vs baseline: 1.5578x; 1.0090x over previous
//
#include <hip/hip_runtime.h>

#define NF 8
#define RMASK 255
#define SENT 0xFFFFFFFFu

typedef float f2 __attribute__((ext_vector_type(2)));
typedef float f4 __attribute__((ext_vector_type(4)));

template <int CTRL>
__device__ __forceinline__ float qp(float x) {
  return __int_as_float(
      __builtin_amdgcn_update_dpp(0, __float_as_int(x), CTRL, 0xF, 0xF, true));
}

// Raw barrier: LDS-ordering only (global ops stay in flight across phases).
__device__ __forceinline__ void wg_barrier() {
  asm volatile("s_waitcnt lgkmcnt(0)" ::: "memory");
  __builtin_amdgcn_s_barrier();
  __builtin_amdgcn_sched_barrier(0);
}

#define WAIT_VM(N) asm volatile("s_waitcnt vmcnt(" #N ")" ::: "memory")

// Coherent (device-scope) ops: sc0 sc1 -> to/from the coherence point.
__device__ __forceinline__ float ld_cohf(const float* p) {
  float v;
  asm volatile("global_load_dword %0, %1, off sc0 sc1" : "=v"(v) : "v"(p) : "memory");
  return v;
}
__device__ __forceinline__ int ld_cohi(const int* p) {
  int v;
  asm volatile("global_load_dword %0, %1, off sc0 sc1" : "=v"(v) : "v"(p) : "memory");
  return v;
}
__device__ __forceinline__ void st_cohf(float* p, float v) {
  asm volatile("global_store_dword %0, %1, off sc0 sc1" :: "v"(p), "v"(v) : "memory");
}
__device__ __forceinline__ void st_cohi(int* p, int v) {
  asm volatile("global_store_dword %0, %1, off sc0 sc1" :: "v"(p), "v"(v) : "memory");
}

// R20 = R18 byte-identical (verified PASS @9878us, absmax 0.0) — BANKED.
// Session ledger: R12/R13/R16/R17/R19 all failed deep-flight transport
// (op-count pollution / unverified cpol / multi-phase pending registers).
// R18 is the only transport upgrade that passed: flag-free sentinel ring,
// 1-phase pending, value-based commit. Residual b1 overhead (~450cy/phase
// by subtraction) needs a rocprof capture of THIS kernel before any
// further surgery — further blind protocol redesign is negative-EV.
//
// Design (R18): d_ws ring pre-poisoned 0xFFFFFFFF (NaN; |h0|<1 so never
// legit). Slot = step (NO reuse, ~5.2MB) -> b0 pub is a bare coherent-store
// stream with ZERO polls/flags -> never blocks -> deadlock-free by
// construction. b1 dma speculatively ld_cohf's the next <=4 slots each
// phase (1-phase pending registers — the only depth that ever passed),
// WAIT_VM(0) at top (~free: loads a full phase old), commits the
// all-lanes-non-sentinel prefix to LDS, retries the rest. Validity is in
// the data itself: no op-counted vmcnt, no flag line, no global_load_lds.
// Head in b1 wv5; ring1/b2 deleted. Cell math byte-identical R14/R7.
// Fallback (small ws): R14's flag+backpressure dma.
__global__ __launch_bounds__(384, 1) void decoder_p20(
    const float* __restrict__ h0in, const float* __restrict__ c0in,
    const float* __restrict__ diffp, const float* __restrict__ target,
    const float* __restrict__ Wih0, const float* __restrict__ Whh0,
    const float* __restrict__ bih0, const float* __restrict__ bhh0,
    const float* __restrict__ Wih1, const float* __restrict__ Whh1,
    const float* __restrict__ bih1, const float* __restrict__ bhh1,
    const float* __restrict__ Whid, const float* __restrict__ bhidp,
    const float* __restrict__ Woutp, const float* __restrict__ boutp,
    float* __restrict__ outp, float* __restrict__ ws, const int T,
    const int BP)
{
  const int tid = threadIdx.x;
  const int wv  = tid >> 6;
  const int l   = tid & 63;
  const int q   = l >> 2;
  const int k   = l & 3;
  const int u   = 16 * (wv & 3) + q;
  const int r   = 64 * k + u;
  const bool isk0 = (k == 0);
  const float am = (k == 2) ? 2.0f : 1.0f;
  const float ab = (k == 2) ? -1.0f : 0.0f;

  __shared__ alignas(256) float h0r[4][64];        // b0
  __shared__ alignas(256) float tbuf[2][32 * NF];  // b0
  __shared__ alignas(256) float h0loc[16][64];     // b1
  __shared__ alignas(256) float h1r[4][64];        // b1
  __shared__ alignas(256) float hidS[4][32];       // b1
  __shared__ alignas(256) float obuf[64 * NF];     // b1
  __shared__ float ldspad[20480];                  // 80KB: 1 block/CU

  if (T < 0) {  // never true; keeps ldspad allocated
    ldspad[tid] = h0in[tid];
    __syncthreads();
    outp[0] = ldspad[383 - tid];
  }

  int* flag0p = (int*)ws;          // BP mode only (line A)
  int* cons0p = (int*)ws + 64;     // BP mode only (line B)
  float* ring0 = ws + 256;         // slot=step (BP=0) or slot=step&255 (BP=1)

  if (blockIdx.x == 0) {
    // ================= BLOCK 0 : layer 0 =================
    f2 wreg[36];
    float b_ = 0.f, xd = 0.f, cS = 0.f, hS = 0.f, xc = 0.f;
    if (wv < 4) {
      #pragma unroll
      for (int j = 0; j < 4; ++j) {
        const int row = 64 * ((k + j) & 3) + u;
        const float* rp = Whh0 + row * 64 + 16 * k;
        #pragma unroll
        for (int c = 0; c < 4; ++c) {
          f4 v = *(const f4*)(rp + 4 * ((c + k) & 3));
          wreg[8 * j + 2 * c]     = v.lo;
          wreg[8 * j + 2 * c + 1] = v.hi;
        }
      }
      b_ = bih0[r] + bhh0[r];
      const float* ra = Wih0 + r * 14;
      #pragma unroll
      for (int c = 0; c < 4; ++c) wreg[32 + c] = (f2){ra[2 * c], ra[2 * c + 1]};
      #pragma unroll
      for (int m = 0; m < 6; ++m) xd += ra[8 + m] * diffp[m];
      if (isk0) cS = c0in[u];
      if (wv == 0) h0r[3][l] = h0in[l];
    } else if (wv == 5) {
      if (l < T) {  // seed tbuf rows 0..63 (both buffers)
        *(f4*)&((float*)tbuf)[l * 8]     = *(const f4*)&target[l * 8];
        *(f4*)&((float*)tbuf)[l * 8 + 4] = *(const f4*)&target[l * 8 + 4];
      }
    }
    __syncthreads();
    if (wv < 4) __builtin_amdgcn_s_setprio(1);

    int cons0L = 0;
    f4 tr0 = {0.f, 0.f, 0.f, 0.f}, tr1 = {0.f, 0.f, 0.f, 0.f};
    for (int t = 0; t <= T; ++t) {
      if (wv < 4) {
        if (t < T) {
          const float* base = &h0r[(t - 1) & 3][16 * k];
          f2 P0 = {0.f,0.f}, P1 = {0.f,0.f}, P2 = {0.f,0.f}, P3 = {0.f,0.f};
          #pragma unroll
          for (int c = 0; c < 4; ++c) {
            f4 v = *(const f4*)(base + 4 * ((c + k) & 3));
            P0 += wreg[2*c] * v.lo;      P0 += wreg[2*c+1] * v.hi;
            P1 += wreg[8+2*c] * v.lo;    P1 += wreg[8+2*c+1] * v.hi;
            P2 += wreg[16+2*c] * v.lo;   P2 += wreg[16+2*c+1] * v.hi;
            P3 += wreg[24+2*c] * v.lo;   P3 += wreg[24+2*c+1] * v.hi;
          }
          float p0 = P0.x + P0.y, p1 = P1.x + P1.y;
          float p2 = P2.x + P2.y, p3 = P3.x + P3.y;
          float g = ((p0 + qp<0x39>(p3)) + (qp<0x4E>(p2) + qp<0x93>(p1))) + b_ + xc;
          float e = __expf(-g * am);
          float s = __fdividef(1.0f, 1.0f + e);
          float a = fmaf(s, am, ab);
          float A1 = qp<0xB1>(a), A2 = qp<0x4E>(a), A3 = qp<0x1B>(a);
          if (isk0) {
            cS = A1 * cS + a * A2;
            float e2 = __expf(-2.0f * cS);
            hS = A3 * (__fdividef(2.0f, 1.0f + e2) - 1.0f);
            h0r[t & 3][u] = hS;
          }
        }
        if (t < T - 1) {
          const f4* trow = (const f4*)&tbuf[(t >> 5) & 1][(t & 31) * NF];
          f4 r0 = trow[0], r1 = trow[1];
          f2 s2 = wreg[32] * r0.lo; s2 += wreg[33] * r0.hi;
          s2 += wreg[34] * r1.lo;   s2 += wreg[35] * r1.hi;
          xc = xd + s2.x + s2.y;
        } else xc = 0.f;
      } else if (wv == 4) {
        if (!BP) {
          // ---- primary pub: bare store stream; never blocks ----
          if (t >= 1) {
            float hv = h0r[(t - 1) & 3][l];
            st_cohf(&ring0[(size_t)(t - 1) * 64 + l], hv);
          }
        } else {
          // ---- BP pub (R14-verbatim counts) ----
          if ((t & 3) == 0 && t >= 8) {
            WAIT_VM(4);   // S(t-7) has 6 newer ops -> retired
            if (l == 0) st_cohi(flag0p, t - 6);
          }
          if ((t & 63) == 0 && t > 192) {
            while (t - cons0L > 192) {
              cons0L = ld_cohi(cons0p);
              WAIT_VM(0);
            }
          }
          if (t >= 1) {
            float hv = h0r[(t - 1) & 3][l];
            st_cohf(&ring0[((t - 1) & RMASK) * 64 + l], hv);
          }
        }
      } else {
        // ---- tbuf wave: loads ph8, writes ph26 (own vmcnt domain) ----
        const int ph = t & 31;
        const int cl = (t >> 5) + 1;
        if (l < 32 && cl * 32 < T) {
          if (ph == 8) {
            tr0 = *(const f4*)&target[cl * 256 + l * 8];
            tr1 = *(const f4*)&target[cl * 256 + l * 8 + 4];
          } else if (ph == 26) {
            WAIT_VM(0);
            *(f4*)&tbuf[cl & 1][l * 8]     = tr0;
            *(f4*)&tbuf[cl & 1][l * 8 + 4] = tr1;
          }
        }
      }
      wg_barrier();
    }
    if (BP && wv == 4) {
      WAIT_VM(0);
      if (l == 0) st_cohi(flag0p, T);
    }
    if (wv < 4 && isk0) {
      outp[T * NF + u]       = hS;   // h_final layer 0
      outp[T * NF + 128 + u] = cS;   // c_final layer 0
    }
  } else {
    // ================= BLOCK 1 : layer 1 + dma + head =================
    f2 wreg[64];
    f2 wH[16], wO[4];
    float b_ = 0.f, cS = 0.f, hS = 0.f;
    float bhA = 0.f, bhB = 0.f, bo_ = 0.f;
    if (wv < 4) {
      const float* Wsrc = (k < 2) ? Wih1 : Whh1;
      const int co = 32 * (k & 1);
      #pragma unroll
      for (int j = 0; j < 4; ++j) {
        const int row = 64 * ((k + j) & 3) + u;
        const float* rp = Wsrc + row * 64 + co;
        #pragma unroll
        for (int c = 0; c < 8; ++c) {
          f4 v = *(const f4*)(rp + 4 * ((c + 2 * k) & 7));
          wreg[16 * j + 2 * c]     = v.lo;
          wreg[16 * j + 2 * c + 1] = v.hi;
        }
      }
      b_ = bih1[r] + bhh1[r];
      if (isk0) cS = c0in[64 + u];
      if (wv == 0) h1r[3][l] = h0in[64 + l];
    } else if (wv == 5) {
      // head weights (R15-verbatim layouts)
      #pragma unroll
      for (int i = 0; i < 2; ++i) {
        const float* rp = Whid + (2 * q + i) * 64 + 16 * k;
        #pragma unroll
        for (int c = 0; c < 4; ++c) {
          f4 v = *(const f4*)(rp + 4 * ((c + k) & 3));
          wH[8 * i + 2 * c]     = v.lo;
          wH[8 * i + 2 * c + 1] = v.hi;
        }
      }
      bhA = bhidp[2 * q];
      bhB = bhidp[2 * q + 1];
      if (q < 8) {
        const float* rp = Woutp + q * 32 + 8 * k;
        #pragma unroll
        for (int c = 0; c < 2; ++c) {
          f4 v = *(const f4*)(rp + 4 * ((c + k) & 1));
          wO[2 * c]     = v.lo;
          wO[2 * c + 1] = v.hi;
        }
        bo_ = boutp[q];
      }
    }
    __syncthreads();

    // ---- dma prologue ----
    float pb0 = 0.f, pb1 = 0.f, pb2 = 0.f, pb3 = 0.f;
    int ns = 0, fillW = 0, flagL = 0, F_pend = 0, nPend = 0;
    if (wv == 4) {
      if (!BP) {
        const int pf = (T < 8) ? T : 8;   // sentinel-poll prefill
        while (fillW < pf) {
          float v = ld_cohf(&ring0[(size_t)fillW * 64 + l]);
          WAIT_VM(0);
          if (__all(__float_as_uint(v) != SENT)) {
            h0loc[fillW & 15][l] = v;
            ++fillW;
          }
        }
      } else {
        const int pf = (T < 4) ? T : 4;   // flag-gated prefill (R14)
        while (flagL < pf) {
          flagL = ld_cohi(flag0p);
          WAIT_VM(0);
        }
        for (int s = 0; s < pf; ++s) {
          float v = ld_cohf(&ring0[(s & RMASK) * 64 + l]);
          WAIT_VM(0);
          h0loc[s & 15][l] = v;
        }
        fillW = pf;
        F_pend = flagL;
      }
    }
    __syncthreads();
    if (wv < 4) __builtin_amdgcn_s_setprio(1);

    const int pend_ = T + 4;
    for (int p = 0; p <= pend_; ++p) {
      if (wv < 4) {
        // -------- L1 cell (R14-verbatim; zero vmem) --------
        if (p < T) {
          const float* base = (k < 2) ? &h0loc[p & 15][32 * (k & 1)]
                                      : &h1r[(p - 1) & 3][32 * (k & 1)];
          f2 P0 = {0.f,0.f}, P1 = {0.f,0.f}, P2 = {0.f,0.f}, P3 = {0.f,0.f};
          #pragma unroll
          for (int c = 0; c < 8; ++c) {
            f4 v = *(const f4*)(base + 4 * ((c + 2 * k) & 7));
            P0 += wreg[2*c] * v.lo;      P0 += wreg[2*c+1] * v.hi;
            P1 += wreg[16+2*c] * v.lo;   P1 += wreg[16+2*c+1] * v.hi;
            P2 += wreg[32+2*c] * v.lo;   P2 += wreg[32+2*c+1] * v.hi;
            P3 += wreg[48+2*c] * v.lo;   P3 += wreg[48+2*c+1] * v.hi;
          }
          float p0 = P0.x + P0.y, p1 = P1.x + P1.y;
          float p2 = P2.x + P2.y, p3 = P3.x + P3.y;
          float g = ((p0 + qp<0x39>(p3)) + (qp<0x4E>(p2) + qp<0x93>(p1))) + b_;
          float e = __expf(-g * am);
          float s = __fdividef(1.0f, 1.0f + e);
          float a = fmaf(s, am, ab);
          float A1 = qp<0xB1>(a), A2 = qp<0x4E>(a), A3 = qp<0x1B>(a);
          if (isk0) {
            cS = A1 * cS + a * A2;
            float e2 = __expf(-2.0f * cS);
            hS = A3 * (__fdividef(2.0f, 1.0f + e2) - 1.0f);
            h1r[p & 3][u] = hS;
          }
        }
      } else if (wv == 4) {
        if (!BP) {
          // ---- primary dma: sentinel ring, all waits VM(0) ----
          WAIT_VM(0);   // pends issued last phase: ~1 phase old, ~free
          // commit valid prefix (partial visibility -> per-lane check)
          bool stop = false;
          if (ns > 0 && !stop) {
            if (__all(__float_as_uint(pb0) != SENT)) { h0loc[fillW & 15][l] = pb0; ++fillW; }
            else stop = true;
          }
          if (ns > 1 && !stop) {
            if (__all(__float_as_uint(pb1) != SENT)) { h0loc[fillW & 15][l] = pb1; ++fillW; }
            else stop = true;
          }
          if (ns > 2 && !stop) {
            if (__all(__float_as_uint(pb2) != SENT)) { h0loc[fillW & 15][l] = pb2; ++fillW; }
            else stop = true;
          }
          if (ns > 3 && !stop) {
            if (__all(__float_as_uint(pb3) != SENT)) { h0loc[fillW & 15][l] = pb3; ++fillW; }
            else stop = true;
          }
          ns = 0;
          // emergency: cells at p+1 need step p+1 (blocking poll; b0 free-runs)
          {
            int lim = p + 2; if (lim > T) lim = T;
            while (fillW < lim) {
              float v = ld_cohf(&ring0[(size_t)fillW * 64 + l]);
              WAIT_VM(0);
              if (__all(__float_as_uint(v) != SENT)) {
                h0loc[fillW & 15][l] = v;
                ++fillW;
              }
            }
          }
          // speculative issue (<=4; cap p+14 keeps LDS ring safe)
          {
            int want = p + 14; if (want > T) want = T;
            int n = want - fillW; if (n < 0) n = 0; if (n > 4) n = 4;
            if (n > 0) pb0 = ld_cohf(&ring0[(size_t)(fillW + 0) * 64 + l]);
            if (n > 1) pb1 = ld_cohf(&ring0[(size_t)(fillW + 1) * 64 + l]);
            if (n > 2) pb2 = ld_cohf(&ring0[(size_t)(fillW + 2) * 64 + l]);
            if (n > 3) pb3 = ld_cohf(&ring0[(size_t)(fillW + 3) * 64 + l]);
            ns = n;
          }
        } else {
          // ---- BP dma (R14-verbatim minus ring1; all top-waits VM(0)) ----
          WAIT_VM(0);
          if (nPend > 0) h0loc[(fillW + 0) & 15][l] = pb0;
          if (nPend > 1) h0loc[(fillW + 1) & 15][l] = pb1;
          if (nPend > 2) h0loc[(fillW + 2) & 15][l] = pb2;
          if (nPend > 3) h0loc[(fillW + 3) & 15][l] = pb3;
          fillW += nPend;
          nPend = 0;
          if ((p & 3) == 1) flagL = F_pend;
          {  // emergency
            int need = p + 2; if (need > T) need = T;
            while (fillW < need) {
              while (flagL < fillW + 1) {
                flagL = ld_cohi(flag0p);
                WAIT_VM(0);
              }
              float v = ld_cohf(&ring0[(fillW & RMASK) * 64 + l]);
              WAIT_VM(0);
              h0loc[fillW & 15][l] = v;
              ++fillW;
            }
          }
          if ((p & 3) == 0) F_pend = ld_cohi(flag0p);  // adopt at p+1 (drained)
          {
            int want = flagL;
            if (want > p + 10) want = p + 10;
            if (want > T) want = T;
            int n = want - fillW;
            if (n < 0) n = 0;
            if (n > 4) n = 4;
            if (n > 0) pb0 = ld_cohf(&ring0[((fillW + 0) & RMASK) * 64 + l]);
            if (n > 1) pb1 = ld_cohf(&ring0[((fillW + 1) & RMASK) * 64 + l]);
            if (n > 2) pb2 = ld_cohf(&ring0[((fillW + 2) & RMASK) * 64 + l]);
            if (n > 3) pb3 = ld_cohf(&ring0[((fillW + 3) & RMASK) * 64 + l]);
            nPend = n;
          }
          if ((p & 63) == 32 && l == 0) st_cohi(cons0p, fillW);
        }
      } else {
        // -------- head (R15-verbatim): hid[p-2], out[p-4], stores -------
        const int sH = p - 2;
        if (sH >= 0 && sH < T) {
          const float* hp = &h1r[sH & 3][16 * k];
          f2 pa = {0.f,0.f}, pb = {0.f,0.f};
          #pragma unroll
          for (int c = 0; c < 4; ++c) {
            f4 v = *(const f4*)(hp + 4 * ((c + k) & 3));
            pa += wH[2*c] * v.lo;     pa += wH[2*c+1] * v.hi;
            pb += wH[8+2*c] * v.lo;   pb += wH[8+2*c+1] * v.hi;
          }
          float sa = pa.x + pa.y; sa += qp<0xB1>(sa); sa += qp<0x4E>(sa);
          float sb = pb.x + pb.y; sb += qp<0xB1>(sb); sb += qp<0x4E>(sb);
          if (isk0) *(f2*)&hidS[sH & 3][2 * q] = (f2){sa + bhA, sb + bhB};
        }
        const int sO = p - 4;
        if (sO >= 0 && sO < T && q < 8) {
          const float* hp = &hidS[sO & 3][8 * k];
          f2 po = {0.f,0.f};
          #pragma unroll
          for (int c = 0; c < 2; ++c) {
            f4 v = *(const f4*)(hp + 4 * ((c + k) & 1));
            po += wO[2*c] * v.lo; po += wO[2*c+1] * v.hi;
          }
          float so = po.x + po.y; so += qp<0xB1>(so); so += qp<0x4E>(so);
          if (isk0) obuf[(sO & 63) * NF + q] = rintf(so + bo_);
        }
        if (l >= 32 && (p & 31) == 5 && p >= 37) {
          const int j = l - 32;
          #pragma unroll
          for (int ii = 0; ii < 2; ++ii) {
            const int fidx = 2 * j + ii;
            const int s  = (p - 37) + (fidx >> 1);
            const int c4 = (fidx & 1) * 4;
            *(f4*)&outp[s * NF + c4] = *(const f4*)&obuf[(s & 63) * NF + c4];
          }
        }
      }
      wg_barrier();
    }
    if (wv < 4 && isk0) {
      outp[T * NF + 64 + u]  = hS;   // h_final layer 1
      outp[T * NF + 192 + u] = cS;   // c_final layer 1
    }
    __syncthreads();
    {
      int s0 = T - 64;
      if (s0 < 0) s0 = 0;
      for (int idx = tid; idx < (T - s0) * NF; idx += 384) {
        const int s = s0 + (idx >> 3);
        outp[s * NF + (idx & 7)] = obuf[(s & 63) * NF + (idx & 7)];
      }
    }
  }
}

extern "C" void kernel_launch(void* const* d_in, const int* in_sizes, int n_in,
                              void* d_out, int out_size, void* d_ws, size_t ws_size,
                              hipStream_t stream) {
  const float* h0in   = (const float*)d_in[1];
  const float* c0in   = (const float*)d_in[2];
  const float* diffp  = (const float*)d_in[3];
  const float* target = (const float*)d_in[4];
  const float* Wih0   = (const float*)d_in[5];
  const float* Whh0   = (const float*)d_in[6];
  const float* bih0   = (const float*)d_in[7];
  const float* bhh0   = (const float*)d_in[8];
  const float* Wih1   = (const float*)d_in[9];
  const float* Whh1   = (const float*)d_in[10];
  const float* bih1   = (const float*)d_in[11];
  const float* bhh1   = (const float*)d_in[12];
  const float* Whid   = (const float*)d_in[13];
  const float* bhidp  = (const float*)d_in[14];
  const float* Woutp  = (const float*)d_in[15];
  const float* boutp  = (const float*)d_in[16];
  float* outp = (float*)d_out;
  const int T = in_sizes[4] / NF;

  // Primary: no-reuse sentinel ring (needs ~5.2MB). Fallback: R14 protocol.
  const size_t need = ((size_t)256 + (size_t)T * 64) * 4;
  int BP;
  if (ws_size >= need) {
    BP = 0;
    hipMemsetAsync(d_ws, 0xFF, need, stream);   // poison ring with NaN sentinel
  } else {
    BP = 1;
    hipMemsetAsync(d_ws, 0, 1024, stream);      // zero flag + cons lines
  }

  decoder_p20<<<dim3(2), dim3(384), 0, stream>>>(
      h0in, c0in, diffp, target,
      Wih0, Whh0, bih0, bhh0,
      Wih1, Whh1, bih1, bhh1,
      Whid, bhidp, Woutp, boutp,
      outp, (float*)d_ws, T, BP);
}